// Round 5
// baseline (1188.034 us; speedup 1.0000x reference)
//
#include <hip/hip_runtime.h>
#include <math.h>

#define Q 2048
#define NOBS 8192
#define BS 128
#define NSTEPS 16   // Q / BS

// ---------------------------------------------------------------------------
// readlane broadcast: lane index is a compile-time literal after unrolling,
// so this is a VALU->SGPR read (no LDS/ds_bpermute 120cy latency).
__device__ __forceinline__ float rl(float v, int l) {
  return __int_as_float(__builtin_amdgcn_readlane(__float_as_int(v), l));
}

// ---------------------------------------------------------------------------
__device__ __forceinline__ float block_sum256(float v, volatile float* red) {
  int tid = threadIdx.x;
#pragma unroll
  for (int o = 32; o > 0; o >>= 1) v += __shfl_down(v, o);
  __syncthreads();
  if ((tid & 63) == 0) red[tid >> 6] = v;
  __syncthreads();
  return red[0] + red[1] + red[2] + red[3];
}

// ---------------------------------------------------------------------------
// In-register 64x64 Cholesky, one wave, lane = row. Broadcasts via readlane.
// rr[64] MUST stay in VGPRs (spill = 25x slowdown, measured round 3).
__device__ __forceinline__ float chol64_reg(float rr[64], int lane) {
  float dv = 1.0f;
#pragma unroll
  for (int j = 0; j < 64; ++j) {
    float vjj = rl(rr[j], j);
    float invd = rsqrtf(vjj);
    float lij = rr[j] * invd;   // lane j gets sqrt(vjj)
    rr[j] = lij;
    if (lane == j) dv = lij;
#pragma unroll
    for (int k = j + 1; k < 64; ++k) rr[k] -= lij * rl(lij, k);
  }
  return dv;
}

// ---------------------------------------------------------------------------
// Blocked 128x128 Cholesky of src (stride sstride) into dstage (stride 128,
// lower triangle valid). Uses LDS: LT[64*64] (zero-padded strictly-lower L11
// transposed), Xs[64*65], invDs[64]. Accumulates sum(log diag) into scal[3].
// Caller provides 256 threads; wave0 does the serial parts.
__device__ __forceinline__ void factor128_from(
    const float* src, int sstride, float* dstage,
    float* LT, float* Xs, float* invDs, float* scal) {
  int tid = threadIdx.x;
  int lane = tid & 63;
  float lg = 0.0f;

  // ---- F1: chol A11 (wave0, rows in registers) ----
  if (tid < 64) {
    float rr[64];
    const float* row = src + (size_t)lane * sstride;
#pragma unroll
    for (int k4 = 0; k4 < 16; ++k4) {
      float4 v = *(const float4*)(row + k4 * 4);
      rr[k4 * 4 + 0] = v.x; rr[k4 * 4 + 1] = v.y;
      rr[k4 * 4 + 2] = v.z; rr[k4 * 4 + 3] = v.w;
    }
    __builtin_amdgcn_s_setprio(1);
    float dv = chol64_reg(rr, lane);
    __builtin_amdgcn_s_setprio(0);
    invDs[lane] = 1.0f / dv;
    lg = logf(dv);
    // LT[p][k] = L11[k][p] for p<k, else 0 (zero-pad lets F2 use float4)
#pragma unroll
    for (int p = 0; p < 64; ++p)
      LT[p * 64 + lane] = (p < lane) ? rr[p] : 0.0f;
#pragma unroll
    for (int k4 = 0; k4 < 16; ++k4) {
      float4 st;
      st.x = rr[k4 * 4 + 0]; st.y = rr[k4 * 4 + 1];
      st.z = rr[k4 * 4 + 2]; st.w = rr[k4 * 4 + 3];
      *(float4*)(dstage + lane * 128 + k4 * 4) = st;
    }
  }
  __syncthreads();

  // ---- F2: TRSM A21 (wave0, lane = row, 64 indep rows) ----
  if (tid < 64) {
    float rr2[64];
    const float* row = src + (size_t)(64 + lane) * sstride;
#pragma unroll
    for (int k4 = 0; k4 < 16; ++k4) {
      float4 v = *(const float4*)(row + k4 * 4);
      rr2[k4 * 4 + 0] = v.x; rr2[k4 * 4 + 1] = v.y;
      rr2[k4 * 4 + 2] = v.z; rr2[k4 * 4 + 3] = v.w;
    }
    __builtin_amdgcn_s_setprio(1);
#pragma unroll
    for (int p = 0; p < 64; ++p) {
      float xp = rr2[p] * invDs[p];
      rr2[p] = xp;
#pragma unroll
      for (int k4 = 0; k4 < 16; ++k4) {
        if (k4 * 4 + 3 > p) {        // chunks fully below p skipped; zeros pad
          float4 l4 = *(const float4*)&LT[p * 64 + k4 * 4];
          rr2[k4 * 4 + 0] -= xp * l4.x;
          rr2[k4 * 4 + 1] -= xp * l4.y;
          rr2[k4 * 4 + 2] -= xp * l4.z;
          rr2[k4 * 4 + 3] -= xp * l4.w;
        }
      }
    }
    __builtin_amdgcn_s_setprio(0);
#pragma unroll
    for (int k = 0; k < 64; ++k) Xs[lane * 65 + k] = rr2[k];
#pragma unroll
    for (int k4 = 0; k4 < 16; ++k4) {
      float4 st;
      st.x = rr2[k4 * 4 + 0]; st.y = rr2[k4 * 4 + 1];
      st.z = rr2[k4 * 4 + 2]; st.w = rr2[k4 * 4 + 3];
      *(float4*)(dstage + (64 + lane) * 128 + k4 * 4) = st;
    }
  }
  __syncthreads();

  // ---- F3: A22' = A22 - X X^T  (all 256 threads, 4x4 each) ----
  {
    int tx = tid & 15, ty = tid >> 4;
    float a2[4][4];
#pragma unroll
    for (int i = 0; i < 4; ++i)
#pragma unroll
      for (int j = 0; j < 4; ++j) a2[i][j] = 0.f;
    for (int p = 0; p < 64; ++p) {
      float xa[4], xb[4];
#pragma unroll
      for (int i = 0; i < 4; ++i) xa[i] = Xs[(ty * 4 + i) * 65 + p];
#pragma unroll
      for (int j = 0; j < 4; ++j) xb[j] = Xs[(tx * 4 + j) * 65 + p];
#pragma unroll
      for (int i = 0; i < 4; ++i)
#pragma unroll
        for (int j = 0; j < 4; ++j) a2[i][j] += xa[i] * xb[j];
    }
#pragma unroll
    for (int i = 0; i < 4; ++i) {
      int gr = 64 + ty * 4 + i;
      const float* sp = src + (size_t)gr * sstride + 64 + tx * 4;
      float4 s4 = *(const float4*)sp;
      float4 o;
      o.x = s4.x - a2[i][0]; o.y = s4.y - a2[i][1];
      o.z = s4.z - a2[i][2]; o.w = s4.w - a2[i][3];
      *(float4*)(dstage + gr * 128 + 64 + tx * 4) = o;
    }
  }
  __syncthreads();
  __builtin_amdgcn_fence(__ATOMIC_ACQUIRE, "workgroup");

  // ---- F4: chol A22 (wave0) ----
  if (tid < 64) {
    float rr3[64];
    const float* row = dstage + (64 + lane) * 128 + 64;
#pragma unroll
    for (int k4 = 0; k4 < 16; ++k4) {
      float4 v = *(const float4*)(row + k4 * 4);
      rr3[k4 * 4 + 0] = v.x; rr3[k4 * 4 + 1] = v.y;
      rr3[k4 * 4 + 2] = v.z; rr3[k4 * 4 + 3] = v.w;
    }
    __builtin_amdgcn_s_setprio(1);
    float dv = chol64_reg(rr3, lane);
    __builtin_amdgcn_s_setprio(0);
    lg += logf(dv);
#pragma unroll
    for (int k4 = 0; k4 < 16; ++k4) {
      float4 st;
      st.x = rr3[k4 * 4 + 0]; st.y = rr3[k4 * 4 + 1];
      st.z = rr3[k4 * 4 + 2]; st.w = rr3[k4 * 4 + 3];
      *(float4*)(dstage + (64 + lane) * 128 + 64 + k4 * 4) = st;
    }
#pragma unroll
    for (int o = 32; o > 0; o >>= 1) lg += __shfl_down(lg, o);
    if (lane == 0) atomicAdd(&scal[3], lg);
  }
}

// ---------------------------------------------------------------------------
__global__ __launch_bounds__(256) void obs_kernel(
    const float* __restrict__ yt, const float* __restrict__ yp,
    const int* __restrict__ zidx, const float* __restrict__ s2e_p,
    const float* __restrict__ s2b_p, float* __restrict__ t,
    int* __restrict__ cnt, float* __restrict__ scal) {
  __shared__ float red[4];
  int i = blockIdx.x * 256 + threadIdx.x;
  float s2e = s2e_p[0], s2b = s2b_p[0];
  float sig2 = s2e + s2b;
  float r = yt[i] - yp[i];
  float e = erff(r * rsqrtf(2.0f * sig2));
  float u = 0.5f * (e + 1.0f);
  u = fminf(fmaxf(u, 1e-5f), 1.0f - 1e-5f);
  float m = erfinvf(2.0f * u - 1.0f) * 1.4142135623730951f;
  float slp = -0.5f * logf(2.0f * 3.14159265358979f * sig2) - r * r / (2.0f * sig2);
  int z = zidx[i];
  atomicAdd(&t[z], m);
  atomicAdd(&cnt[z], 1);
  float s1 = block_sum256(slp, red);
  float s2 = block_sum256(m * m, red);
  if (threadIdx.x == 0) {
    atomicAdd(&scal[0], s1);   // sum_log_pdf
    atomicAdd(&scal[1], s2);   // m'm
  }
}

// ---------------------------------------------------------------------------
// Fused: build G row j AND the matvec w = K t in one pass over dist row j
// (saves a dispatch + one full 16MB re-read of dist).
__global__ __launch_bounds__(256) void build_mv(
    const float* __restrict__ dist, const float* __restrict__ s2e_p,
    const float* __restrict__ s2b_p, const float* __restrict__ ell_p,
    const int* __restrict__ cnt, const float* __restrict__ t,
    float* __restrict__ G, float* __restrict__ z, float* __restrict__ scal) {
  __shared__ float red[4];
  int j = blockIdx.x;
  float s2e = s2e_p[0], s2b = s2b_p[0], ell = ell_p[0];
  float sig2 = s2e + s2b;
  float ratio = s2b / sig2;
  float diag = s2e / sig2;
  float inv2ell = 1.0f / (2.0f * ell);
  float cj = (float)cnt[j];
  const float* drow = dist + (size_t)j * Q;
  float* grow = G + (size_t)j * Q;
  float s = 0.0f;
  for (int k = threadIdx.x; k < Q; k += 256) {
    float e = expf(-drow[k] * inv2ell);
    s += e * t[k];
    float g = sqrtf(cj * (float)cnt[k]) * (ratio * e);
    if (j == k) g += diag;
    grow[k] = g;
  }
  float tot = block_sum256(s, red);
  if (threadIdx.x == 0) {
    float wj = ratio * tot;
    z[j] = sqrtf(cj) * wj;          // b = W^{1/2} w
    atomicAdd(&scal[2], t[j] * wj); // t.w
  }
}

// ---------------------------------------------------------------------------
// Factor the first 128x128 diag tile of G into dstage.
__global__ __launch_bounds__(256, 1) void potrf_first(
    const float* __restrict__ G, float* __restrict__ dstage,
    float* __restrict__ scal) {
  __shared__ __align__(16) float smem[64 * 64 + 64 * 65];
  __shared__ float invDs[64];
  factor128_from(G, Q, dstage, smem, smem + 64 * 64, invDs, scal);
}

// ---------------------------------------------------------------------------
// TRSM of the panel below the staged 128x128 factor (+ z as a virtual row).
// One row per wave; 2 cols/lane; readlane chain (128 steps, ~0.8us latency).
__global__ __launch_bounds__(256) void trsm_step(
    float* __restrict__ G, float* __restrict__ z,
    const float* __restrict__ dstage, int j0, int Rtot) {
  __shared__ float shL[128 * 129];   // stride 129: chain reads conflict-free
  int tid = threadIdx.x;
#pragma unroll
  for (int it = 0; it < 16; ++it) {
    int idx = it * 256 + tid;        // 4096 float4 chunks
    int r = idx >> 5, c4 = (idx & 31) * 4;
    float4 v = *(const float4*)(dstage + r * 128 + c4);
    shL[r * 129 + c4 + 0] = v.x; shL[r * 129 + c4 + 1] = v.y;
    shL[r * 129 + c4 + 2] = v.z; shL[r * 129 + c4 + 3] = v.w;
  }
  __syncthreads();
  int lane = tid & 63, wv = tid >> 6;
  int ri = blockIdx.x * 4 + wv;
  if (ri >= Rtot) return;
  int r = j0 + BS + ri;
  float* grow = (r < Q) ? (G + (size_t)r * Q + j0) : (z + j0);
  float a0 = grow[lane];
  float a1 = grow[64 + lane];
  float inv0 = 1.0f / shL[lane * 129 + lane];
  float inv1 = 1.0f / shL[(64 + lane) * 129 + 64 + lane];
#pragma unroll
  for (int p = 0; p < 64; ++p) {
    float xp = rl(a0, p) * rl(inv0, p);
    if (lane > p) a0 -= xp * shL[lane * 129 + p];
    a1 -= xp * shL[(64 + lane) * 129 + p];   // 64+lane > p always
  }
#pragma unroll
  for (int p = 0; p < 64; ++p) {
    float xp = rl(a1, p) * rl(inv1, p);
    if (lane > p) a1 -= xp * shL[(64 + lane) * 129 + 64 + p];
  }
  grow[lane] = a0 * inv0;
  grow[64 + lane] = a1 * inv1;
}

// ---------------------------------------------------------------------------
// Per-step trailing work at 128 granularity, one job per block:
//   job 0              : lookahead — update NEXT 128-diag tile (1-block GEMM)
//                        and factor it into dstage.
//   job in [1, ntri)   : 128x128 trailing SYRK tiles (lower incl. diag tiles).
//   job in [ntri, +nb) : z forward-substitution updates per trailing block.
__global__ __launch_bounds__(256, 1) void syrk_step(
    float* __restrict__ G, float* __restrict__ z, float* __restrict__ dstage,
    float* __restrict__ scal, int j0, int ntri, int nb) {
  __shared__ __align__(16) float smem[2 * 32 * 132];  // 33.8 KB union
  __shared__ float invDs[64];
  __shared__ float z1s[128];
  int tid = threadIdx.x;
  int bx = blockIdx.x;
  float* shA = smem;
  float* shB = smem + 32 * 132;

  if (bx >= ntri) {
    // ---- z update for trailing block bk ----
    int zj = bx - ntri;
    int C0 = j0 + BS + zj * BS;
    if (tid < 128) z1s[tid] = z[j0 + tid];
    __syncthreads();
    int rw = tid >> 1, part = tid & 1;
    const float* Lr = G + (size_t)(C0 + rw) * Q + j0;
    float ssum = 0.f;
    for (int p = part; p < 128; p += 2) ssum += Lr[p] * z1s[p];
    ssum += __shfl_down(ssum, 1);
    if (part == 0) z[C0 + rw] -= ssum;
    return;
  }

  int tx = tid & 15, ty = tid >> 4;
  float acc[8][8];
#pragma unroll
  for (int i = 0; i < 8; ++i)
#pragma unroll
    for (int j = 0; j < 8; ++j) acc[i][j] = 0.f;

  if (bx == 0) {
    // ---- lookahead: next diag tile update (symmetric GEMM) + factor ----
    int D0 = j0 + BS;
    for (int kk = 0; kk < 4; ++kk) {
#pragma unroll
      for (int it = 0; it < 4; ++it) {
        int idx = it * 256 + tid;      // 1024 float4: 128 rows x 8 chunks
        int r = idx >> 3, c4 = (idx & 7) * 4;
        float4 v = *(const float4*)(G + (size_t)(D0 + r) * Q + j0 + kk * 32 + c4);
        shA[(c4 + 0) * 132 + r] = v.x; shA[(c4 + 1) * 132 + r] = v.y;
        shA[(c4 + 2) * 132 + r] = v.z; shA[(c4 + 3) * 132 + r] = v.w;
      }
      __syncthreads();
#pragma unroll
      for (int p = 0; p < 32; ++p) {
        float4 a0 = *(const float4*)&shA[p * 132 + ty * 8];
        float4 a1 = *(const float4*)&shA[p * 132 + ty * 8 + 4];
        float4 b0 = *(const float4*)&shA[p * 132 + tx * 8];
        float4 b1 = *(const float4*)&shA[p * 132 + tx * 8 + 4];
        float av[8] = {a0.x, a0.y, a0.z, a0.w, a1.x, a1.y, a1.z, a1.w};
        float bv[8] = {b0.x, b0.y, b0.z, b0.w, b1.x, b1.y, b1.z, b1.w};
#pragma unroll
        for (int i = 0; i < 8; ++i)
#pragma unroll
          for (int j = 0; j < 8; ++j) acc[i][j] += av[i] * bv[j];
      }
      __syncthreads();
    }
    // updated diag tile -> dstage
#pragma unroll
    for (int i = 0; i < 8; ++i) {
      const float* gp = G + (size_t)(D0 + ty * 8 + i) * Q + D0 + tx * 8;
      float4 g0 = *(const float4*)gp;
      float4 g1 = *(const float4*)(gp + 4);
      float4 o0, o1;
      o0.x = g0.x - acc[i][0]; o0.y = g0.y - acc[i][1];
      o0.z = g0.z - acc[i][2]; o0.w = g0.w - acc[i][3];
      o1.x = g1.x - acc[i][4]; o1.y = g1.y - acc[i][5];
      o1.z = g1.z - acc[i][6]; o1.w = g1.w - acc[i][7];
      *(float4*)(dstage + (ty * 8 + i) * 128 + tx * 8) = o0;
      *(float4*)(dstage + (ty * 8 + i) * 128 + tx * 8 + 4) = o1;
    }
    __syncthreads();
    __builtin_amdgcn_fence(__ATOMIC_ACQUIRE, "workgroup");
    factor128_from(dstage, 128, dstage, smem, smem + 64 * 64, invDs, scal);
    return;
  }

  // ---- trailing SYRK tile (bi, bk), bi >= bk ----
  int job = bx;
  int bi = (int)((sqrtf(8.0f * (float)job + 1.0f) - 1.0f) * 0.5f);
  while ((bi + 1) * (bi + 2) / 2 <= job) ++bi;
  while (bi * (bi + 1) / 2 > job) --bi;
  int bk = job - bi * (bi + 1) / 2;
  int R0 = j0 + BS + bi * BS;
  int C0 = j0 + BS + bk * BS;
  bool sym = (bi == bk);

  for (int kk = 0; kk < 4; ++kk) {
#pragma unroll
    for (int it = 0; it < 4; ++it) {
      int idx = it * 256 + tid;
      int r = idx >> 3, c4 = (idx & 7) * 4;
      float4 v = *(const float4*)(G + (size_t)(R0 + r) * Q + j0 + kk * 32 + c4);
      shA[(c4 + 0) * 132 + r] = v.x; shA[(c4 + 1) * 132 + r] = v.y;
      shA[(c4 + 2) * 132 + r] = v.z; shA[(c4 + 3) * 132 + r] = v.w;
      if (!sym) {
        float4 u = *(const float4*)(G + (size_t)(C0 + r) * Q + j0 + kk * 32 + c4);
        shB[(c4 + 0) * 132 + r] = u.x; shB[(c4 + 1) * 132 + r] = u.y;
        shB[(c4 + 2) * 132 + r] = u.z; shB[(c4 + 3) * 132 + r] = u.w;
      }
    }
    __syncthreads();
    const float* sB = sym ? shA : shB;
#pragma unroll
    for (int p = 0; p < 32; ++p) {
      float4 a0 = *(const float4*)&shA[p * 132 + ty * 8];
      float4 a1 = *(const float4*)&shA[p * 132 + ty * 8 + 4];
      float4 b0 = *(const float4*)&sB[p * 132 + tx * 8];
      float4 b1 = *(const float4*)&sB[p * 132 + tx * 8 + 4];
      float av[8] = {a0.x, a0.y, a0.z, a0.w, a1.x, a1.y, a1.z, a1.w};
      float bv[8] = {b0.x, b0.y, b0.z, b0.w, b1.x, b1.y, b1.z, b1.w};
#pragma unroll
      for (int i = 0; i < 8; ++i)
#pragma unroll
        for (int j = 0; j < 8; ++j) acc[i][j] += av[i] * bv[j];
    }
    __syncthreads();
  }
#pragma unroll
  for (int i = 0; i < 8; ++i) {
    float* gp = G + (size_t)(R0 + ty * 8 + i) * Q + C0 + tx * 8;
    float4 g0 = *(const float4*)gp;
    float4 g1 = *(const float4*)(gp + 4);
    g0.x -= acc[i][0]; g0.y -= acc[i][1]; g0.z -= acc[i][2]; g0.w -= acc[i][3];
    g1.x -= acc[i][4]; g1.y -= acc[i][5]; g1.z -= acc[i][6]; g1.w -= acc[i][7];
    *(float4*)gp = g0;
    *(float4*)(gp + 4) = g1;
  }
}

// ---------------------------------------------------------------------------
__global__ __launch_bounds__(256) void final_assemble(
    const float* __restrict__ z, const float* __restrict__ scal,
    const float* __restrict__ s2e_p, const float* __restrict__ s2b_p,
    float* __restrict__ out) {
  __shared__ float red[4];
  int tid = threadIdx.x;
  float bv = 0.f;
  for (int i = tid; i < Q; i += 256) {
    float zi = z[i];
    bv += zi * zi;
  }
  float bvs = block_sum256(bv, red);
  if (tid == 0) {
    float s2e = s2e_p[0], s2b = s2b_p[0];
    float sig2 = s2e + s2b;
    float c = s2e / sig2;
    float slp = scal[0], mtm = scal[1];
    float tw = scal[2], sl = scal[3];
    float tty = (tw - bvs) / c;          // t' y
    float mrm = (mtm - tty) / c;         // m' R^{-1} m
    float logdetR = (float)(NOBS - Q) * logf(c) + 2.0f * sl;
    out[0] = 0.5f * logdetR + 0.5f * mrm - 0.5f * mtm + 0.5f * slp;
  }
}

// ---------------------------------------------------------------------------
extern "C" void kernel_launch(void* const* d_in, const int* in_sizes, int n_in,
                              void* d_out, int out_size, void* d_ws, size_t ws_size,
                              hipStream_t stream) {
  const float* yt   = (const float*)d_in[0];
  const float* yp   = (const float*)d_in[1];
  const int*   zidx = (const int*)d_in[2];
  const float* dist = (const float*)d_in[3];
  const float* s2e  = (const float*)d_in[4];
  const float* s2b  = (const float*)d_in[5];
  const float* ell  = (const float*)d_in[6];

  float* ws   = (float*)d_ws;
  float* G    = ws;                         // Q*Q floats = 16 MB
  float* z    = ws + (size_t)Q * Q;         // Q
  float* t    = z + Q;                      // Q
  int*   cnt  = (int*)(t + Q);              // Q ints
  float* scal = t + 2 * Q;                  // 8: slp, mtm, tw, sumlogL
  float* dstage = scal + 8;                 // 128*128 staged diag factor

  // zero t, cnt, scal
  hipMemsetAsync(t, 0, (2 * Q + 8) * sizeof(float), stream);

  obs_kernel<<<NOBS / 256, 256, 0, stream>>>(yt, yp, zidx, s2e, s2b, t, cnt, scal);
  build_mv<<<Q, 256, 0, stream>>>(dist, s2e, s2b, ell, cnt, t, G, z, scal);

  potrf_first<<<1, 256, 0, stream>>>(G, dstage, scal);

  for (int s = 0; s < NSTEPS; ++s) {
    int j0 = s * BS;
    int ntr = Q - j0 - BS;
    int Rtot = ntr + 1;                 // trailing rows + z row
    int nb = ntr / BS;
    trsm_step<<<(Rtot + 3) / 4, 256, 0, stream>>>(G, z, dstage, j0, Rtot);
    if (nb > 0) {
      int ntri = nb * (nb + 1) / 2;
      syrk_step<<<ntri + nb, 256, 0, stream>>>(G, z, dstage, scal, j0, ntri, nb);
    }
  }

  final_assemble<<<1, 256, 0, stream>>>(z, scal, s2e, s2b, (float*)d_out);
}

// Round 6
// 1186.849 us; speedup vs baseline: 1.0010x; 1.0010x over previous
//
#include <hip/hip_runtime.h>
#include <math.h>

#define Q 2048
#define NOBS 8192
#define BS 128
#define NSTEPS 16   // Q / BS

// ---------------------------------------------------------------------------
// readlane broadcast: lane index is a compile-time literal after unrolling,
// so this is a VALU->SGPR read (no LDS/ds_bpermute 120cy latency).
__device__ __forceinline__ float rl(float v, int l) {
  return __int_as_float(__builtin_amdgcn_readlane(__float_as_int(v), l));
}

// ---------------------------------------------------------------------------
__device__ __forceinline__ float block_sum256(float v, volatile float* red) {
  int tid = threadIdx.x;
#pragma unroll
  for (int o = 32; o > 0; o >>= 1) v += __shfl_down(v, o);
  __syncthreads();
  if ((tid & 63) == 0) red[tid >> 6] = v;
  __syncthreads();
  return red[0] + red[1] + red[2] + red[3];
}

// ---------------------------------------------------------------------------
// In-register 64x64 Cholesky, one wave, lane = row. Broadcasts via readlane.
// rr[64] MUST stay in VGPRs (spill = 25x slowdown, measured round 3).
__device__ __forceinline__ float chol64_reg(float rr[64], int lane) {
  float dv = 1.0f;
#pragma unroll
  for (int j = 0; j < 64; ++j) {
    float vjj = rl(rr[j], j);
    float invd = rsqrtf(vjj);
    float lij = rr[j] * invd;   // lane j gets sqrt(vjj)
    rr[j] = lij;
    if (lane == j) dv = lij;
#pragma unroll
    for (int k = j + 1; k < 64; ++k) rr[k] -= lij * rl(lij, k);
  }
  return dv;
}

// ---------------------------------------------------------------------------
// Blocked 128x128 Cholesky of src (stride sstride) into dstage (stride 128,
// lower triangle valid). Uses LDS: LT[64*64] (zero-padded strictly-lower L11
// transposed), Xs[64*65], invDs[64]. Accumulates sum(log diag) into scal[3].
// Caller provides 256 threads; wave0 does the serial parts.
__device__ __forceinline__ void factor128_from(
    const float* src, int sstride, float* dstage,
    float* LT, float* Xs, float* invDs, float* scal) {
  int tid = threadIdx.x;
  int lane = tid & 63;
  float lg = 0.0f;

  // ---- F1: chol A11 (wave0, rows in registers) ----
  if (tid < 64) {
    float rr[64];
    const float* row = src + (size_t)lane * sstride;
#pragma unroll
    for (int k4 = 0; k4 < 16; ++k4) {
      float4 v = *(const float4*)(row + k4 * 4);
      rr[k4 * 4 + 0] = v.x; rr[k4 * 4 + 1] = v.y;
      rr[k4 * 4 + 2] = v.z; rr[k4 * 4 + 3] = v.w;
    }
    __builtin_amdgcn_s_setprio(1);
    float dv = chol64_reg(rr, lane);
    __builtin_amdgcn_s_setprio(0);
    invDs[lane] = 1.0f / dv;
    lg = logf(dv);
    // LT[p][k] = L11[k][p] for p<k, else 0 (zero-pad lets F2 use float4)
#pragma unroll
    for (int p = 0; p < 64; ++p)
      LT[p * 64 + lane] = (p < lane) ? rr[p] : 0.0f;
#pragma unroll
    for (int k4 = 0; k4 < 16; ++k4) {
      float4 st;
      st.x = rr[k4 * 4 + 0]; st.y = rr[k4 * 4 + 1];
      st.z = rr[k4 * 4 + 2]; st.w = rr[k4 * 4 + 3];
      *(float4*)(dstage + lane * 128 + k4 * 4) = st;
    }
  }
  __syncthreads();

  // ---- F2: TRSM A21 (wave0, lane = row, 64 indep rows) ----
  if (tid < 64) {
    float rr2[64];
    const float* row = src + (size_t)(64 + lane) * sstride;
#pragma unroll
    for (int k4 = 0; k4 < 16; ++k4) {
      float4 v = *(const float4*)(row + k4 * 4);
      rr2[k4 * 4 + 0] = v.x; rr2[k4 * 4 + 1] = v.y;
      rr2[k4 * 4 + 2] = v.z; rr2[k4 * 4 + 3] = v.w;
    }
    __builtin_amdgcn_s_setprio(1);
#pragma unroll
    for (int p = 0; p < 64; ++p) {
      float xp = rr2[p] * invDs[p];
      rr2[p] = xp;
#pragma unroll
      for (int k4 = 0; k4 < 16; ++k4) {
        if (k4 * 4 + 3 > p) {        // chunks fully below p skipped; zeros pad
          float4 l4 = *(const float4*)&LT[p * 64 + k4 * 4];
          rr2[k4 * 4 + 0] -= xp * l4.x;
          rr2[k4 * 4 + 1] -= xp * l4.y;
          rr2[k4 * 4 + 2] -= xp * l4.z;
          rr2[k4 * 4 + 3] -= xp * l4.w;
        }
      }
    }
    __builtin_amdgcn_s_setprio(0);
#pragma unroll
    for (int k = 0; k < 64; ++k) Xs[lane * 65 + k] = rr2[k];
#pragma unroll
    for (int k4 = 0; k4 < 16; ++k4) {
      float4 st;
      st.x = rr2[k4 * 4 + 0]; st.y = rr2[k4 * 4 + 1];
      st.z = rr2[k4 * 4 + 2]; st.w = rr2[k4 * 4 + 3];
      *(float4*)(dstage + (64 + lane) * 128 + k4 * 4) = st;
    }
  }
  __syncthreads();

  // ---- F3: A22' = A22 - X X^T  (all 256 threads, 4x4 each) ----
  {
    int tx = tid & 15, ty = tid >> 4;
    float a2[4][4];
#pragma unroll
    for (int i = 0; i < 4; ++i)
#pragma unroll
      for (int j = 0; j < 4; ++j) a2[i][j] = 0.f;
    for (int p = 0; p < 64; ++p) {
      float xa[4], xb[4];
#pragma unroll
      for (int i = 0; i < 4; ++i) xa[i] = Xs[(ty * 4 + i) * 65 + p];
#pragma unroll
      for (int j = 0; j < 4; ++j) xb[j] = Xs[(tx * 4 + j) * 65 + p];
#pragma unroll
      for (int i = 0; i < 4; ++i)
#pragma unroll
        for (int j = 0; j < 4; ++j) a2[i][j] += xa[i] * xb[j];
    }
#pragma unroll
    for (int i = 0; i < 4; ++i) {
      int gr = 64 + ty * 4 + i;
      const float* sp = src + (size_t)gr * sstride + 64 + tx * 4;
      float4 s4 = *(const float4*)sp;
      float4 o;
      o.x = s4.x - a2[i][0]; o.y = s4.y - a2[i][1];
      o.z = s4.z - a2[i][2]; o.w = s4.w - a2[i][3];
      *(float4*)(dstage + gr * 128 + 64 + tx * 4) = o;
    }
  }
  __syncthreads();
  __builtin_amdgcn_fence(__ATOMIC_ACQUIRE, "workgroup");

  // ---- F4: chol A22 (wave0) ----
  if (tid < 64) {
    float rr3[64];
    const float* row = dstage + (64 + lane) * 128 + 64;
#pragma unroll
    for (int k4 = 0; k4 < 16; ++k4) {
      float4 v = *(const float4*)(row + k4 * 4);
      rr3[k4 * 4 + 0] = v.x; rr3[k4 * 4 + 1] = v.y;
      rr3[k4 * 4 + 2] = v.z; rr3[k4 * 4 + 3] = v.w;
    }
    __builtin_amdgcn_s_setprio(1);
    float dv = chol64_reg(rr3, lane);
    __builtin_amdgcn_s_setprio(0);
    lg += logf(dv);
#pragma unroll
    for (int k4 = 0; k4 < 16; ++k4) {
      float4 st;
      st.x = rr3[k4 * 4 + 0]; st.y = rr3[k4 * 4 + 1];
      st.z = rr3[k4 * 4 + 2]; st.w = rr3[k4 * 4 + 3];
      *(float4*)(dstage + (64 + lane) * 128 + 64 + k4 * 4) = st;
    }
#pragma unroll
    for (int o = 32; o > 0; o >>= 1) lg += __shfl_down(lg, o);
    if (lane == 0) atomicAdd(&scal[3], lg);
  }
}

// ---------------------------------------------------------------------------
__global__ __launch_bounds__(256) void obs_kernel(
    const float* __restrict__ yt, const float* __restrict__ yp,
    const int* __restrict__ zidx, const float* __restrict__ s2e_p,
    const float* __restrict__ s2b_p, float* __restrict__ t,
    int* __restrict__ cnt, float* __restrict__ scal) {
  __shared__ float red[4];
  int i = blockIdx.x * 256 + threadIdx.x;
  float s2e = s2e_p[0], s2b = s2b_p[0];
  float sig2 = s2e + s2b;
  float r = yt[i] - yp[i];
  float e = erff(r * rsqrtf(2.0f * sig2));
  float u = 0.5f * (e + 1.0f);
  u = fminf(fmaxf(u, 1e-5f), 1.0f - 1e-5f);
  float m = erfinvf(2.0f * u - 1.0f) * 1.4142135623730951f;
  float slp = -0.5f * logf(2.0f * 3.14159265358979f * sig2) - r * r / (2.0f * sig2);
  int z = zidx[i];
  atomicAdd(&t[z], m);
  atomicAdd(&cnt[z], 1);
  float s1 = block_sum256(slp, red);
  float s2 = block_sum256(m * m, red);
  if (threadIdx.x == 0) {
    atomicAdd(&scal[0], s1);   // sum_log_pdf
    atomicAdd(&scal[1], s2);   // m'm
  }
}

// ---------------------------------------------------------------------------
// Fused: build G row j AND the matvec w = K t in one pass over dist row j.
__global__ __launch_bounds__(256) void build_mv(
    const float* __restrict__ dist, const float* __restrict__ s2e_p,
    const float* __restrict__ s2b_p, const float* __restrict__ ell_p,
    const int* __restrict__ cnt, const float* __restrict__ t,
    float* __restrict__ G, float* __restrict__ z, float* __restrict__ scal) {
  __shared__ float red[4];
  int j = blockIdx.x;
  float s2e = s2e_p[0], s2b = s2b_p[0], ell = ell_p[0];
  float sig2 = s2e + s2b;
  float ratio = s2b / sig2;
  float diag = s2e / sig2;
  float inv2ell = 1.0f / (2.0f * ell);
  float cj = (float)cnt[j];
  const float* drow = dist + (size_t)j * Q;
  float* grow = G + (size_t)j * Q;
  float s = 0.0f;
  for (int k = threadIdx.x; k < Q; k += 256) {
    float e = expf(-drow[k] * inv2ell);
    s += e * t[k];
    float g = sqrtf(cj * (float)cnt[k]) * (ratio * e);
    if (j == k) g += diag;
    grow[k] = g;
  }
  float tot = block_sum256(s, red);
  if (threadIdx.x == 0) {
    float wj = ratio * tot;
    z[j] = sqrtf(cj) * wj;          // b = W^{1/2} w
    atomicAdd(&scal[2], t[j] * wj); // t.w
  }
}

// ---------------------------------------------------------------------------
// Factor the first 128x128 diag tile of G into dstage.
__global__ __launch_bounds__(256, 1) void potrf_first(
    const float* __restrict__ G, float* __restrict__ dstage,
    float* __restrict__ scal) {
  __shared__ __align__(16) float smem[64 * 64 + 64 * 65];
  __shared__ float invDs[64];
  factor128_from(G, Q, dstage, smem, smem + 64 * 64, invDs, scal);
}

// ---------------------------------------------------------------------------
// TRSM of the panel below the staged 128x128 factor (+ z as a virtual row).
// One row per wave; 2 cols/lane; readlane chain (128 steps, ~0.8us latency).
__global__ __launch_bounds__(256) void trsm_step(
    float* __restrict__ G, float* __restrict__ z,
    const float* __restrict__ dstage, int j0, int Rtot) {
  __shared__ float shL[128 * 129];   // stride 129: chain reads conflict-free
  int tid = threadIdx.x;
#pragma unroll
  for (int it = 0; it < 16; ++it) {
    int idx = it * 256 + tid;        // 4096 float4 chunks
    int r = idx >> 5, c4 = (idx & 31) * 4;
    float4 v = *(const float4*)(dstage + r * 128 + c4);
    shL[r * 129 + c4 + 0] = v.x; shL[r * 129 + c4 + 1] = v.y;
    shL[r * 129 + c4 + 2] = v.z; shL[r * 129 + c4 + 3] = v.w;
  }
  __syncthreads();
  int lane = tid & 63, wv = tid >> 6;
  int ri = blockIdx.x * 4 + wv;
  if (ri >= Rtot) return;
  int r = j0 + BS + ri;
  float* grow = (r < Q) ? (G + (size_t)r * Q + j0) : (z + j0);
  float a0 = grow[lane];
  float a1 = grow[64 + lane];
  float inv0 = 1.0f / shL[lane * 129 + lane];
  float inv1 = 1.0f / shL[(64 + lane) * 129 + 64 + lane];
#pragma unroll
  for (int p = 0; p < 64; ++p) {
    float xp = rl(a0, p) * rl(inv0, p);
    if (lane > p) a0 -= xp * shL[lane * 129 + p];
    a1 -= xp * shL[(64 + lane) * 129 + p];   // 64+lane > p always
  }
#pragma unroll
  for (int p = 0; p < 64; ++p) {
    float xp = rl(a1, p) * rl(inv1, p);
    if (lane > p) a1 -= xp * shL[(64 + lane) * 129 + 64 + p];
  }
  grow[lane] = a0 * inv0;
  grow[64 + lane] = a1 * inv1;
}

// ---------------------------------------------------------------------------
// Per-step trailing work, one job per block (64x64 tiles, K=128 — restores
// occupancy lost in the 128x128 tiling: s=0 has 496 blocks, not 135):
//   job 0                  : lookahead — update NEXT 128-diag (1-block GEMM)
//                            and factor it into dstage.
//   job in [1, 1+ntri)     : 64x64 trailing SYRK tiles, K=128. Tiles inside
//                            the next-diag region (bi<2 && bk<2) return.
//   job in [1+ntri, +n64)  : z forward-substitution per trailing 64-block.
__global__ __launch_bounds__(256, 1) void syrk_step(
    float* __restrict__ G, float* __restrict__ z, float* __restrict__ dstage,
    float* __restrict__ scal, int j0, int ntri, int n64) {
  __shared__ __align__(16) float smem[8704];   // 34.8 KB union
  __shared__ float invDs[64];
  __shared__ float z1s[128];
  int tid = threadIdx.x;
  int bx = blockIdx.x;

  if (bx == 0) {
    // ---- lookahead: next 128-diag update (symmetric GEMM) + factor ----
    float* shA = smem;                 // 32x132 chunks
    int tx = tid & 15, ty = tid >> 4;
    float acc[8][8];
#pragma unroll
    for (int i = 0; i < 8; ++i)
#pragma unroll
      for (int j = 0; j < 8; ++j) acc[i][j] = 0.f;
    int D0 = j0 + BS;
    for (int kk = 0; kk < 4; ++kk) {
#pragma unroll
      for (int it = 0; it < 4; ++it) {
        int idx = it * 256 + tid;      // 1024 float4: 128 rows x 8 chunks
        int r = idx >> 3, c4 = (idx & 7) * 4;
        float4 v = *(const float4*)(G + (size_t)(D0 + r) * Q + j0 + kk * 32 + c4);
        shA[(c4 + 0) * 132 + r] = v.x; shA[(c4 + 1) * 132 + r] = v.y;
        shA[(c4 + 2) * 132 + r] = v.z; shA[(c4 + 3) * 132 + r] = v.w;
      }
      __syncthreads();
#pragma unroll
      for (int p = 0; p < 32; ++p) {
        float4 a0 = *(const float4*)&shA[p * 132 + ty * 8];
        float4 a1 = *(const float4*)&shA[p * 132 + ty * 8 + 4];
        float4 b0 = *(const float4*)&shA[p * 132 + tx * 8];
        float4 b1 = *(const float4*)&shA[p * 132 + tx * 8 + 4];
        float av[8] = {a0.x, a0.y, a0.z, a0.w, a1.x, a1.y, a1.z, a1.w};
        float bv[8] = {b0.x, b0.y, b0.z, b0.w, b1.x, b1.y, b1.z, b1.w};
#pragma unroll
        for (int i = 0; i < 8; ++i)
#pragma unroll
          for (int j = 0; j < 8; ++j) acc[i][j] += av[i] * bv[j];
      }
      __syncthreads();
    }
#pragma unroll
    for (int i = 0; i < 8; ++i) {
      const float* gp = G + (size_t)(D0 + ty * 8 + i) * Q + D0 + tx * 8;
      float4 g0 = *(const float4*)gp;
      float4 g1 = *(const float4*)(gp + 4);
      float4 o0, o1;
      o0.x = g0.x - acc[i][0]; o0.y = g0.y - acc[i][1];
      o0.z = g0.z - acc[i][2]; o0.w = g0.w - acc[i][3];
      o1.x = g1.x - acc[i][4]; o1.y = g1.y - acc[i][5];
      o1.z = g1.z - acc[i][6]; o1.w = g1.w - acc[i][7];
      *(float4*)(dstage + (ty * 8 + i) * 128 + tx * 8) = o0;
      *(float4*)(dstage + (ty * 8 + i) * 128 + tx * 8 + 4) = o1;
    }
    __syncthreads();
    __builtin_amdgcn_fence(__ATOMIC_ACQUIRE, "workgroup");
    factor128_from(dstage, 128, dstage, smem, smem + 64 * 64, invDs, scal);
    return;
  }

  if (bx >= 1 + ntri) {
    // ---- z update for trailing 64-block, K=128 ----
    int zj = bx - 1 - ntri;
    int C0 = j0 + BS + zj * 64;
    if (tid < 128) z1s[tid] = z[j0 + tid];
    __syncthreads();
    int rw = tid >> 2, part = tid & 3;
    const float* Lr = G + (size_t)(C0 + rw) * Q + j0;
    float ssum = 0.f;
    for (int p = part; p < 128; p += 4) ssum += Lr[p] * z1s[p];
    ssum += __shfl_down(ssum, 2);
    ssum += __shfl_down(ssum, 1);
    if (part == 0) z[C0 + rw] -= ssum;
    return;
  }

  // ---- trailing 64x64 SYRK tile (bi, bk), bi >= bk, K=128 ----
  int job = bx - 1;
  int bi = (int)((sqrtf(8.0f * (float)job + 1.0f) - 1.0f) * 0.5f);
  while ((bi + 1) * (bi + 2) / 2 <= job) ++bi;
  while (bi * (bi + 1) / 2 > job) --bi;
  int bk = job - bi * (bi + 1) / 2;
  if (bi < 2 && bk < 2) return;        // next-diag region: job 0 owns it
  int R0 = j0 + BS + bi * 64;
  int C0 = j0 + BS + bk * 64;
  bool sym = (bi == bk);
  float* shA = smem;                   // 64x68
  float* shB = smem + 64 * 68;         // 64x68

  int tx = tid & 15, ty = tid >> 4;
  float acc[4][4] = {{0.f}};
  for (int kk = 0; kk < 2; ++kk) {
#pragma unroll
    for (int it = 0; it < 4; ++it) {
      int idx = it * 256 + tid;        // 1024 16B chunks: 64 rows x 16 chunks
      int r = idx >> 4, c4 = (idx & 15) * 4;
      float4 v = *(const float4*)(G + (size_t)(R0 + r) * Q + j0 + kk * 64 + c4);
      shA[(c4 + 0) * 68 + r] = v.x; shA[(c4 + 1) * 68 + r] = v.y;
      shA[(c4 + 2) * 68 + r] = v.z; shA[(c4 + 3) * 68 + r] = v.w;
      if (!sym) {
        float4 u = *(const float4*)(G + (size_t)(C0 + r) * Q + j0 + kk * 64 + c4);
        shB[(c4 + 0) * 68 + r] = u.x; shB[(c4 + 1) * 68 + r] = u.y;
        shB[(c4 + 2) * 68 + r] = u.z; shB[(c4 + 3) * 68 + r] = u.w;
      }
    }
    __syncthreads();
    const float* sB = sym ? shA : shB;
#pragma unroll
    for (int p = 0; p < 64; ++p) {
      float4 a4 = *(const float4*)&shA[p * 68 + ty * 4];
      float4 b4 = *(const float4*)&sB[p * 68 + tx * 4];
      float av[4] = {a4.x, a4.y, a4.z, a4.w};
      float bv[4] = {b4.x, b4.y, b4.z, b4.w};
#pragma unroll
      for (int i = 0; i < 4; ++i)
#pragma unroll
        for (int jj = 0; jj < 4; ++jj) acc[i][jj] += av[i] * bv[jj];
    }
    __syncthreads();
  }
#pragma unroll
  for (int i = 0; i < 4; ++i) {
    float* gp = G + (size_t)(R0 + ty * 4 + i) * Q + C0 + tx * 4;
    float4 g = *(const float4*)gp;
    g.x -= acc[i][0]; g.y -= acc[i][1];
    g.z -= acc[i][2]; g.w -= acc[i][3];
    *(float4*)gp = g;
  }
}

// ---------------------------------------------------------------------------
__global__ __launch_bounds__(256) void final_assemble(
    const float* __restrict__ z, const float* __restrict__ scal,
    const float* __restrict__ s2e_p, const float* __restrict__ s2b_p,
    float* __restrict__ out) {
  __shared__ float red[4];
  int tid = threadIdx.x;
  float bv = 0.f;
  for (int i = tid; i < Q; i += 256) {
    float zi = z[i];
    bv += zi * zi;
  }
  float bvs = block_sum256(bv, red);
  if (tid == 0) {
    float s2e = s2e_p[0], s2b = s2b_p[0];
    float sig2 = s2e + s2b;
    float c = s2e / sig2;
    float slp = scal[0], mtm = scal[1];
    float tw = scal[2], sl = scal[3];
    float tty = (tw - bvs) / c;          // t' y
    float mrm = (mtm - tty) / c;         // m' R^{-1} m
    float logdetR = (float)(NOBS - Q) * logf(c) + 2.0f * sl;
    out[0] = 0.5f * logdetR + 0.5f * mrm - 0.5f * mtm + 0.5f * slp;
  }
}

// ---------------------------------------------------------------------------
extern "C" void kernel_launch(void* const* d_in, const int* in_sizes, int n_in,
                              void* d_out, int out_size, void* d_ws, size_t ws_size,
                              hipStream_t stream) {
  const float* yt   = (const float*)d_in[0];
  const float* yp   = (const float*)d_in[1];
  const int*   zidx = (const int*)d_in[2];
  const float* dist = (const float*)d_in[3];
  const float* s2e  = (const float*)d_in[4];
  const float* s2b  = (const float*)d_in[5];
  const float* ell  = (const float*)d_in[6];

  float* ws   = (float*)d_ws;
  float* G    = ws;                         // Q*Q floats = 16 MB
  float* z    = ws + (size_t)Q * Q;         // Q
  float* t    = z + Q;                      // Q
  int*   cnt  = (int*)(t + Q);              // Q ints
  float* scal = t + 2 * Q;                  // 8: slp, mtm, tw, sumlogL
  float* dstage = scal + 8;                 // 128*128 staged diag factor

  // zero t, cnt, scal
  hipMemsetAsync(t, 0, (2 * Q + 8) * sizeof(float), stream);

  obs_kernel<<<NOBS / 256, 256, 0, stream>>>(yt, yp, zidx, s2e, s2b, t, cnt, scal);
  build_mv<<<Q, 256, 0, stream>>>(dist, s2e, s2b, ell, cnt, t, G, z, scal);

  potrf_first<<<1, 256, 0, stream>>>(G, dstage, scal);

  for (int s = 0; s < NSTEPS; ++s) {
    int j0 = s * BS;
    int ntr = Q - j0 - BS;
    int Rtot = ntr + 1;                 // trailing rows + z row
    trsm_step<<<(Rtot + 3) / 4, 256, 0, stream>>>(G, z, dstage, j0, Rtot);
    if (ntr > 0) {
      int n64 = ntr / 64;
      int ntri = n64 * (n64 + 1) / 2;
      syrk_step<<<1 + ntri + n64, 256, 0, stream>>>(G, z, dstage, scal, j0,
                                                    ntri, n64);
    }
  }

  final_assemble<<<1, 256, 0, stream>>>(z, scal, s2e, s2b, (float*)d_out);
}

// Round 7
// 1037.622 us; speedup vs baseline: 1.1450x; 1.1438x over previous
//
#include <hip/hip_runtime.h>
#include <math.h>

#define Q 2048
#define NOBS 8192

// ---------------------------------------------------------------------------
// readlane broadcast: lane index is a compile-time literal after unrolling,
// so this is a VALU->SGPR read (no LDS/ds_bpermute 120cy latency).
__device__ __forceinline__ float rl(float v, int l) {
  return __int_as_float(__builtin_amdgcn_readlane(__float_as_int(v), l));
}

// ---------------------------------------------------------------------------
__device__ __forceinline__ float block_sum256(float v, volatile float* red) {
  int tid = threadIdx.x;
#pragma unroll
  for (int o = 32; o > 0; o >>= 1) v += __shfl_down(v, o);
  __syncthreads();
  if ((tid & 63) == 0) red[tid >> 6] = v;
  __syncthreads();
  return red[0] + red[1] + red[2] + red[3];
}

// ---------------------------------------------------------------------------
// In-register 64x64 Cholesky, one wave, lane = row. Broadcasts via readlane.
// rr[64] MUST stay in VGPRs (spill = 25x slowdown, measured round 3).
__device__ __forceinline__ float chol64_reg(float rr[64], int lane) {
  float dv = 1.0f;
#pragma unroll
  for (int j = 0; j < 64; ++j) {
    float vjj = rl(rr[j], j);
    float invd = rsqrtf(vjj);
    float lij = rr[j] * invd;   // lane j gets sqrt(vjj)
    rr[j] = lij;
    if (lane == j) dv = lij;
#pragma unroll
    for (int k = j + 1; k < 64; ++k) rr[k] -= lij * rl(lij, k);
  }
  return dv;
}

// ---------------------------------------------------------------------------
// Point-to-point sync: producer publishes with agent-release fence (wbl2)
// + device-scope atomic add; consumer spins (relaxed atomic load) then
// issues ONE agent-acquire fence (inv). Same fence pattern as round 2
// (correctness-proven); co-residency guaranteed by grid<=512 @ 2 blocks/CU.
__device__ __forceinline__ void wait_flag(int* f, int target) {
  while (__hip_atomic_load(f, __ATOMIC_RELAXED, __HIP_MEMORY_SCOPE_AGENT) <
         target)
    __builtin_amdgcn_s_sleep(8);
}

// ---------------------------------------------------------------------------
__global__ __launch_bounds__(256) void obs_kernel(
    const float* __restrict__ yt, const float* __restrict__ yp,
    const int* __restrict__ zidx, const float* __restrict__ s2e_p,
    const float* __restrict__ s2b_p, float* __restrict__ t,
    int* __restrict__ cnt, float* __restrict__ scal) {
  __shared__ float red[4];
  int i = blockIdx.x * 256 + threadIdx.x;
  float s2e = s2e_p[0], s2b = s2b_p[0];
  float sig2 = s2e + s2b;
  float r = yt[i] - yp[i];
  float e = erff(r * rsqrtf(2.0f * sig2));
  float u = 0.5f * (e + 1.0f);
  u = fminf(fmaxf(u, 1e-5f), 1.0f - 1e-5f);
  float m = erfinvf(2.0f * u - 1.0f) * 1.4142135623730951f;
  float slp = -0.5f * logf(2.0f * 3.14159265358979f * sig2) - r * r / (2.0f * sig2);
  int z = zidx[i];
  atomicAdd(&t[z], m);
  atomicAdd(&cnt[z], 1);
  float s1 = block_sum256(slp, red);
  float s2 = block_sum256(m * m, red);
  if (threadIdx.x == 0) {
    atomicAdd(&scal[0], s1);   // sum_log_pdf
    atomicAdd(&scal[1], s2);   // m'm
  }
}

// ---------------------------------------------------------------------------
// Fused: build G row j AND the matvec w = K t in one pass over dist row j.
__global__ __launch_bounds__(256) void build_mv(
    const float* __restrict__ dist, const float* __restrict__ s2e_p,
    const float* __restrict__ s2b_p, const float* __restrict__ ell_p,
    const int* __restrict__ cnt, const float* __restrict__ t,
    float* __restrict__ G, float* __restrict__ z, float* __restrict__ scal) {
  __shared__ float red[4];
  int j = blockIdx.x;
  float s2e = s2e_p[0], s2b = s2b_p[0], ell = ell_p[0];
  float sig2 = s2e + s2b;
  float ratio = s2b / sig2;
  float diag = s2e / sig2;
  float inv2ell = 1.0f / (2.0f * ell);
  float cj = (float)cnt[j];
  const float* drow = dist + (size_t)j * Q;
  float* grow = G + (size_t)j * Q;
  float s = 0.0f;
  for (int k = threadIdx.x; k < Q; k += 256) {
    float e = expf(-drow[k] * inv2ell);
    s += e * t[k];
    float g = sqrtf(cj * (float)cnt[k]) * (ratio * e);
    if (j == k) g += diag;
    grow[k] = g;
  }
  float tot = block_sum256(s, red);
  if (threadIdx.x == 0) {
    float wj = ratio * tot;
    z[j] = sqrtf(cj) * wj;          // b = W^{1/2} w
    atomicAdd(&scal[2], t[j] * wj); // t.w
  }
}

// ---------------------------------------------------------------------------
// Factor the first 64x64 diag tile of G into dsA; solve z1(0); logdet.
// __launch_bounds__(64,1): single wave, full VGPR budget (no rr spill).
__global__ __launch_bounds__(64, 1) void potrf_first(
    const float* __restrict__ G, float* __restrict__ dsA,
    float* __restrict__ z, float* __restrict__ scal) {
  int lane = threadIdx.x;
  float rr[64];
  const float* row = G + (size_t)lane * Q;
#pragma unroll
  for (int k4 = 0; k4 < 16; ++k4) {
    float4 v = *(const float4*)(row + k4 * 4);
    rr[k4 * 4 + 0] = v.x; rr[k4 * 4 + 1] = v.y;
    rr[k4 * 4 + 2] = v.z; rr[k4 * 4 + 3] = v.w;
  }
  float dv = chol64_reg(rr, lane);
#pragma unroll
  for (int k4 = 0; k4 < 16; ++k4) {
    float4 st;
    st.x = rr[k4 * 4 + 0]; st.y = rr[k4 * 4 + 1];
    st.z = rr[k4 * 4 + 2]; st.w = rr[k4 * 4 + 3];
    *(float4*)(dsA + lane * 64 + k4 * 4) = st;
  }
  float lg = logf(dv);
#pragma unroll
  for (int o = 32; o > 0; o >>= 1) lg += __shfl_down(lg, o);
  if (lane == 0) atomicAdd(&scal[3], lg);
  // solve z1(0) = L^{-1} z[0:64]
  float a = z[lane];
  float myinv = 1.0f / dv;
#pragma unroll
  for (int p = 0; p < 64; ++p) {
    float xp = rl(a, p) * rl(myinv, p);
    if (lane > p) a -= xp * rr[p];
  }
  z[lane] = a * myinv;
}

// ---------------------------------------------------------------------------
// One fused step dispatch at 64-granularity. Roles by blockIdx:
//   trsm blocks (producers, NEVER wait): 16 panel rows each vs dsR; after
//     storing, release-fence + flags[rowblock]++ (target 4 per step).
//   job0 (bx==0): waits rowblock 0 -> diag(s+1) GEMM (K=64) -> chol64 into
//     dsW -> logdet -> z-sub(block s+1) -> solve z1(s+1).
//   tiles (bx in [1,ntri)): wait their 2 rowblocks -> 64x64 K=64 SYRK RMW.
//   z-jobs: wait rowblock bk -> z[C0..] -= X_bk * z1(s).
// mode: 0 = fused; 1 = producers only; 2 = consumers only (for s<4 where
// the fused grid would exceed the 512 guaranteed-resident slots).
__global__ __launch_bounds__(256, 2) void step_kernel(
    float* __restrict__ G, float* __restrict__ z, float* __restrict__ scal,
    const float* __restrict__ dsR, float* __restrict__ dsW,
    int* __restrict__ flags, int j0, int ntri, int n64, int T, int mode) {
  __shared__ __align__(16) float smem[2 * 64 * 68];
  __shared__ float z1s[64];
  __shared__ float z2s[64];
  float* shA = smem;
  float* shB = smem + 64 * 68;
  int tid = threadIdx.x, bx = blockIdx.x;
  int lane = tid & 63, wv = tid >> 6;
  int s1 = (j0 >> 6) + 1;          // absolute index of first trailing block
  int D0 = j0 + 64;
  int ztop = ntri + n64 - 1;

  // ---------------- producers: TRSM of 16 panel rows ----------------
  if (mode == 1 || (mode == 0 && bx >= ztop)) {
    int t = (mode == 1) ? bx : bx - ztop;
    // stage dsR (64x64 row-major) -> shA stride 65
#pragma unroll
    for (int it = 0; it < 4; ++it) {
      int idx = it * 256 + tid;
      int r = idx >> 4, c = (idx & 15) * 4;
      float4 v = *(const float4*)(dsR + r * 64 + c);
      shA[r * 65 + c + 0] = v.x; shA[r * 65 + c + 1] = v.y;
      shA[r * 65 + c + 2] = v.z; shA[r * 65 + c + 3] = v.w;
    }
    __syncthreads();
    int rbase = D0 + t * 16 + wv * 4;
    float* g0 = G + (size_t)(rbase + 0) * Q + j0;
    float* g1 = G + (size_t)(rbase + 1) * Q + j0;
    float* g2 = G + (size_t)(rbase + 2) * Q + j0;
    float* g3 = G + (size_t)(rbase + 3) * Q + j0;
    float a0 = g0[lane], a1 = g1[lane], a2 = g2[lane], a3 = g3[lane];
    float myinv = 1.0f / shA[lane * 65 + lane];
#pragma unroll
    for (int p = 0; p < 64; ++p) {
      float ip = rl(myinv, p);
      float x0 = rl(a0, p) * ip;
      float x1 = rl(a1, p) * ip;
      float x2 = rl(a2, p) * ip;
      float x3 = rl(a3, p) * ip;
      float lv = shA[lane * 65 + p];
      if (lane > p) {
        a0 -= x0 * lv; a1 -= x1 * lv; a2 -= x2 * lv; a3 -= x3 * lv;
      }
    }
    g0[lane] = a0 * myinv; g1[lane] = a1 * myinv;
    g2[lane] = a2 * myinv; g3[lane] = a3 * myinv;
    __syncthreads();   // drains all waves' stores (vmcnt(0) before barrier)
    if (tid == 0) {
      __builtin_amdgcn_fence(__ATOMIC_RELEASE, "agent");   // wbl2
      __hip_atomic_fetch_add(&flags[s1 + (t >> 2)], 1, __ATOMIC_RELAXED,
                             __HIP_MEMORY_SCOPE_AGENT);
    }
    return;
  }

  // ---------------- job0: diag lookahead + z critical path ----------------
  if (bx == 0) {
    if (tid == 0) {
      wait_flag(&flags[s1], T);
      __builtin_amdgcn_fence(__ATOMIC_ACQUIRE, "agent");   // inv
    }
    __syncthreads();
    if (tid < 64) z1s[tid] = z[j0 + tid];
    // stage X0 = panel rows [D0,D0+64) cols [j0,j0+64), transposed
#pragma unroll
    for (int it = 0; it < 4; ++it) {
      int idx = it * 256 + tid;
      int r2 = idx >> 4, c4 = (idx & 15) * 4;
      float4 v = *(const float4*)(G + (size_t)(D0 + r2) * Q + j0 + c4);
      shA[(c4 + 0) * 68 + r2] = v.x; shA[(c4 + 1) * 68 + r2] = v.y;
      shA[(c4 + 2) * 68 + r2] = v.z; shA[(c4 + 3) * 68 + r2] = v.w;
    }
    __syncthreads();
    int tx = tid & 15, ty = tid >> 4;
    float acc[4][4] = {{0.f}};
    for (int p = 0; p < 64; ++p) {
      float4 a4 = *(const float4*)&shA[p * 68 + ty * 4];
      float4 b4 = *(const float4*)&shA[p * 68 + tx * 4];
      float av[4] = {a4.x, a4.y, a4.z, a4.w};
      float bv[4] = {b4.x, b4.y, b4.z, b4.w};
#pragma unroll
      for (int i = 0; i < 4; ++i)
#pragma unroll
        for (int jj = 0; jj < 4; ++jj) acc[i][jj] += av[i] * bv[jj];
    }
    // z-sub for block s+1: z2s[r] = z[D0+r] - X0[r][:].z1
    {
      int rw = tid >> 2, part = tid & 3;
      float ssum = 0.f;
      for (int p = part; p < 64; p += 4) ssum += shA[p * 68 + rw] * z1s[p];
      ssum += __shfl_down(ssum, 2);
      ssum += __shfl_down(ssum, 1);
      if (part == 0) z2s[rw] = z[D0 + rw] - ssum;
    }
    // updated diag tile -> shB (row-major, stride 68)
#pragma unroll
    for (int i = 0; i < 4; ++i) {
      const float* gp = G + (size_t)(D0 + ty * 4 + i) * Q + D0 + tx * 4;
      float4 g = *(const float4*)gp;
      float4 o;
      o.x = g.x - acc[i][0]; o.y = g.y - acc[i][1];
      o.z = g.z - acc[i][2]; o.w = g.w - acc[i][3];
      *(float4*)&shB[(ty * 4 + i) * 68 + tx * 4] = o;
    }
    __syncthreads();
    if (tid < 64) {
      float rr[64];
#pragma unroll
      for (int k4 = 0; k4 < 16; ++k4) {
        float4 v = *(const float4*)&shB[lane * 68 + k4 * 4];
        rr[k4 * 4 + 0] = v.x; rr[k4 * 4 + 1] = v.y;
        rr[k4 * 4 + 2] = v.z; rr[k4 * 4 + 3] = v.w;
      }
      __builtin_amdgcn_s_setprio(1);
      float dv = chol64_reg(rr, lane);
      __builtin_amdgcn_s_setprio(0);
#pragma unroll
      for (int k4 = 0; k4 < 16; ++k4) {
        float4 st;
        st.x = rr[k4 * 4 + 0]; st.y = rr[k4 * 4 + 1];
        st.z = rr[k4 * 4 + 2]; st.w = rr[k4 * 4 + 3];
        *(float4*)(dsW + lane * 64 + k4 * 4) = st;
      }
      float lg = logf(dv);
#pragma unroll
      for (int o = 32; o > 0; o >>= 1) lg += __shfl_down(lg, o);
      if (lane == 0) atomicAdd(&scal[3], lg);
      // solve z1(s+1)
      float a = z2s[lane];
      float myinv = 1.0f / dv;
#pragma unroll
      for (int p = 0; p < 64; ++p) {
        float xp = rl(a, p) * rl(myinv, p);
        if (lane > p) a -= xp * rr[p];
      }
      z[D0 + lane] = a * myinv;
    }
    return;
  }

  // ---------------- tiles: 64x64 K=64 trailing SYRK ----------------
  if (bx < ntri) {
    int job = bx;
    int bi = (int)((sqrtf(8.0f * (float)job + 1.0f) - 1.0f) * 0.5f);
    while ((bi + 1) * (bi + 2) / 2 <= job) ++bi;
    while (bi * (bi + 1) / 2 > job) --bi;
    int bk = job - bi * (bi + 1) / 2;
    if (tid == 0) {
      wait_flag(&flags[s1 + bi], T);
      if (bk != bi) wait_flag(&flags[s1 + bk], T);
      __builtin_amdgcn_fence(__ATOMIC_ACQUIRE, "agent");
    }
    __syncthreads();
    int R0 = D0 + bi * 64, C0 = D0 + bk * 64;
    bool sym = (bi == bk);
#pragma unroll
    for (int it = 0; it < 4; ++it) {
      int idx = it * 256 + tid;
      int r = idx >> 4, c4 = (idx & 15) * 4;
      float4 v = *(const float4*)(G + (size_t)(R0 + r) * Q + j0 + c4);
      shA[(c4 + 0) * 68 + r] = v.x; shA[(c4 + 1) * 68 + r] = v.y;
      shA[(c4 + 2) * 68 + r] = v.z; shA[(c4 + 3) * 68 + r] = v.w;
      if (!sym) {
        float4 u = *(const float4*)(G + (size_t)(C0 + r) * Q + j0 + c4);
        shB[(c4 + 0) * 68 + r] = u.x; shB[(c4 + 1) * 68 + r] = u.y;
        shB[(c4 + 2) * 68 + r] = u.z; shB[(c4 + 3) * 68 + r] = u.w;
      }
    }
    __syncthreads();
    const float* sB = sym ? shA : shB;
    int tx = tid & 15, ty = tid >> 4;
    float acc[4][4] = {{0.f}};
    for (int p = 0; p < 64; ++p) {
      float4 a4 = *(const float4*)&shA[p * 68 + ty * 4];
      float4 b4 = *(const float4*)&sB[p * 68 + tx * 4];
      float av[4] = {a4.x, a4.y, a4.z, a4.w};
      float bv[4] = {b4.x, b4.y, b4.z, b4.w};
#pragma unroll
      for (int i = 0; i < 4; ++i)
#pragma unroll
        for (int jj = 0; jj < 4; ++jj) acc[i][jj] += av[i] * bv[jj];
    }
#pragma unroll
    for (int i = 0; i < 4; ++i) {
      float* gp = G + (size_t)(R0 + ty * 4 + i) * Q + C0 + tx * 4;
      float4 g = *(const float4*)gp;
      g.x -= acc[i][0]; g.y -= acc[i][1];
      g.z -= acc[i][2]; g.w -= acc[i][3];
      *(float4*)gp = g;
    }
    return;
  }

  // ---------------- z-jobs: z[C0..] -= X_bk . z1(s) ----------------
  {
    int bk = bx - ntri + 1;
    if (tid == 0) {
      wait_flag(&flags[s1 + bk], T);
      __builtin_amdgcn_fence(__ATOMIC_ACQUIRE, "agent");
    }
    __syncthreads();
    if (tid < 64) z1s[tid] = z[j0 + tid];
    __syncthreads();
    int C0 = D0 + bk * 64;
    int rw = tid >> 2, part = tid & 3;
    const float* Lr = G + (size_t)(C0 + rw) * Q + j0;
    float ssum = 0.f;
    for (int p = part; p < 64; p += 4) ssum += Lr[p] * z1s[p];
    ssum += __shfl_down(ssum, 2);
    ssum += __shfl_down(ssum, 1);
    if (part == 0) z[C0 + rw] -= ssum;
  }
}

// ---------------------------------------------------------------------------
__global__ __launch_bounds__(256) void final_assemble(
    const float* __restrict__ z, const float* __restrict__ scal,
    const float* __restrict__ s2e_p, const float* __restrict__ s2b_p,
    float* __restrict__ out) {
  __shared__ float red[4];
  int tid = threadIdx.x;
  float bv = 0.f;
  for (int i = tid; i < Q; i += 256) {
    float zi = z[i];
    bv += zi * zi;
  }
  float bvs = block_sum256(bv, red);
  if (tid == 0) {
    float s2e = s2e_p[0], s2b = s2b_p[0];
    float sig2 = s2e + s2b;
    float c = s2e / sig2;
    float slp = scal[0], mtm = scal[1];
    float tw = scal[2], sl = scal[3];
    float tty = (tw - bvs) / c;          // t' y
    float mrm = (mtm - tty) / c;         // m' R^{-1} m
    float logdetR = (float)(NOBS - Q) * logf(c) + 2.0f * sl;
    out[0] = 0.5f * logdetR + 0.5f * mrm - 0.5f * mtm + 0.5f * slp;
  }
}

// ---------------------------------------------------------------------------
extern "C" void kernel_launch(void* const* d_in, const int* in_sizes, int n_in,
                              void* d_out, int out_size, void* d_ws, size_t ws_size,
                              hipStream_t stream) {
  const float* yt   = (const float*)d_in[0];
  const float* yp   = (const float*)d_in[1];
  const int*   zidx = (const int*)d_in[2];
  const float* dist = (const float*)d_in[3];
  const float* s2e  = (const float*)d_in[4];
  const float* s2b  = (const float*)d_in[5];
  const float* ell  = (const float*)d_in[6];

  float* ws   = (float*)d_ws;
  float* G    = ws;                         // Q*Q floats = 16 MB
  float* z    = ws + (size_t)Q * Q;         // Q
  float* t    = z + Q;                      // Q
  int*   cntv = (int*)(t + Q);              // Q ints
  float* scal = t + 2 * Q;                  // 8: slp, mtm, tw, sumlogL
  int*   flags = (int*)(scal + 8);          // 64 row-block flags
  float* dsA  = scal + 8 + 64;              // 64*64 staged diag factor (even s)
  float* dsB  = dsA + 4096;                 // 64*64 staged diag factor (odd s)

  // zero t, cntv, scal, flags
  hipMemsetAsync(t, 0, (2 * Q + 8 + 64) * sizeof(float), stream);

  obs_kernel<<<NOBS / 256, 256, 0, stream>>>(yt, yp, zidx, s2e, s2b, t, cntv, scal);
  build_mv<<<Q, 256, 0, stream>>>(dist, s2e, s2b, ell, cntv, t, G, z, scal);

  potrf_first<<<1, 64, 0, stream>>>(G, dsA, z, scal);

  for (int s = 0; s < 31; ++s) {
    int n64 = 31 - s;
    int ntri = n64 * (n64 + 1) / 2;
    int j0 = s * 64;
    int T = 4 * (s + 1);
    float* dsR = (s & 1) ? dsB : dsA;
    float* dsW = (s & 1) ? dsA : dsB;
    int gfull = ntri + 5 * n64 - 1;   // job0 + (ntri-1) tiles + (n64-1) z + 4*n64 trsm
    if (gfull <= 512) {
      // all blocks guaranteed co-resident (>=2 blocks/CU x 256 CUs)
      step_kernel<<<gfull, 256, 0, stream>>>(G, z, scal, dsR, dsW, flags,
                                             j0, ntri, n64, T, 0);
    } else {
      step_kernel<<<4 * n64, 256, 0, stream>>>(G, z, scal, dsR, dsW, flags,
                                               j0, ntri, n64, T, 1);
      step_kernel<<<ntri + n64 - 1, 256, 0, stream>>>(G, z, scal, dsR, dsW,
                                                      flags, j0, ntri, n64, T, 2);
    }
  }

  final_assemble<<<1, 256, 0, stream>>>(z, scal, s2e, s2b, (float*)d_out);
}